// Round 5
// baseline (2085.236 us; speedup 1.0000x reference)
//
#include <hip/hip_runtime.h>
#include <cstddef>

// (B, C, D, H, W) = (2, 2, 128, 256, 256)
#define BZ   2
#define DV   128
#define HV   256
#define WV   256
#define NP   32
#define NBOX 64                 // BZ*NP seed boxes
#define NIT  10
#define RAD  10
#define BOX  21                 // 2*RAD+1
#define BOX2 441
#define BOX3 9261
#define HWV  65536
#define DHW  ((size_t)DV*HWV)
#define SMOOTH 1e-5f
#define CSTR 28                 // LDS column stride (dwords): 112B -> 16B-aligned
                                // for every t; bank starts {4k} cover all banks
                                // <=2-way across a wave -> conflict-free (m136)
#define NT   448                // 7 waves; 441 active threads (one per (h,w))

// Load/accumulate a 21-float LDS column as 5x b128 + 1x b32 (batched reads,
// single waitcnt; no read/write interleave hazards).
__device__ __forceinline__ void ld_col_add(const float* base, float* r) {
    const float4* s = (const float4*)base;
    float4 q0 = s[0], q1 = s[1], q2 = s[2], q3 = s[3], q4 = s[4];
    float  q5 = base[20];
    r[0]+=q0.x; r[1]+=q0.y; r[2]+=q0.z; r[3]+=q0.w;
    r[4]+=q1.x; r[5]+=q1.y; r[6]+=q1.z; r[7]+=q1.w;
    r[8]+=q2.x; r[9]+=q2.y; r[10]+=q2.z; r[11]+=q2.w;
    r[12]+=q3.x; r[13]+=q3.y; r[14]+=q3.z; r[15]+=q3.w;
    r[16]+=q4.x; r[17]+=q4.y; r[18]+=q4.z; r[19]+=q4.w;
    r[20]+=q5;
}
__device__ __forceinline__ void st_col(float* base, const float* r) {
    float4* s = (float4*)base;
    s[0] = make_float4(r[0], r[1], r[2], r[3]);
    s[1] = make_float4(r[4], r[5], r[6], r[7]);
    s[2] = make_float4(r[8], r[9], r[10], r[11]);
    s[3] = make_float4(r[12], r[13], r[14], r[15]);
    s[4] = make_float4(r[16], r[17], r[18], r[19]);
    base[20] = r[20];
}

// ===========================================================================
// Single kernel, 64 blocks (one per seed box):
//   evolve: u_k = avgpool3(u_{k-1})*prob, 10 steps. Field lives in registers
//     as per-thread d-columns (d-axis sum free); w/h axis sums go through two
//     alternating LDS buffers with vectorized conflict-free column I/O.
//   tail  : fence+counter; last block to arrive computes exact summed-field
//     max for boxes with overlap neighbors (rare), then the eps-corrected
//     normalization recurrence t_N = g_N + eps*g_9 and the eb gather.
__global__ void __launch_bounds__(NT)
cape_kernel(const float* __restrict__ logits,
            const int* __restrict__ ea,
            const int* __restrict__ eb,
            float* __restrict__ out,
            float* __restrict__ u,        // [NBOX][BOX3] tight d*441+h*21+w
            float* __restrict__ g9part,   // [NBOX]
            float* __restrict__ gNpart,   // [NBOX]
            int* __restrict__ dupflag,    // [NBOX]
            unsigned int* __restrict__ counter)
{
    __shared__ __align__(16) float A[BOX2 * CSTR];   // 49392 B
    __shared__ __align__(16) float Bb[BOX2 * CSTR];  // 49392 B
    __shared__ float sred[7], sred2[7];
    __shared__ int sflag, stail;

    const int box = blockIdx.x;
    const int b = box >> 5;
    const int t = threadIdx.x;
    const bool act = (t < BOX2);
    const int hh = t / BOX, ww = t % BOX;

    const int sd = ea[box*3], sh = ea[box*3+1], sw = ea[box*3+2];
    if (t == 0) {
        int dup = 0;
        for (int q = b*NP; q < box; ++q)
            if (ea[q*3] == sd && ea[q*3+1] == sh && ea[q*3+2] == sw) { dup = 1; break; }
        sflag = dup;
        dupflag[box] = dup;
        if (dup) { g9part[box] = 0.f; gNpart[box] = 0.f; }
    }
    __syncthreads();

    float max9 = 0.f, maxN = 0.f;

    if (!sflag) {
        // prob/27 column + field registers
        float p[BOX], c[BOX];
        #pragma unroll
        for (int d = 0; d < BOX; ++d) { p[d] = 0.f; c[d] = 0.f; }
        if (act) {
            const int gh = sh - RAD + hh, gw = sw - RAD + ww;
            if (gh >= 0 && gh < HV && gw >= 0 && gw < WV) {
                const float* lg = logits + (size_t)b * 2 * DHW;
                #pragma unroll
                for (int d = 0; d < BOX; ++d) {
                    int gd = sd - RAD + d;
                    if (gd >= 0 && gd < DV) {
                        size_t off = (size_t)gd * HWV + (size_t)gh * WV + gw;
                        float l0 = lg[off], l1 = lg[off + DHW];
                        p[d] = (1.f/27.f) / (1.f + __expf(l0 - l1));
                    }
                }
            }
            if (hh == RAD && ww == RAD) c[RAD] = 1.0f;   // seed
        }

        for (int k = 0; k < NIT; ++k) {
            // d-sums in registers (free), write column to A
            float ds[BOX];
            ds[0] = c[0] + c[1];
            #pragma unroll
            for (int d = 1; d < BOX-1; ++d) ds[d] = c[d-1] + c[d] + c[d+1];
            ds[BOX-1] = c[BOX-2] + c[BOX-1];
            if (act) st_col(&A[t * CSTR], ds);
            __syncthreads();
            // w-pass: add w+-1 neighbor columns from A (own ds in regs)
            float ws[BOX];
            #pragma unroll
            for (int d = 0; d < BOX; ++d) ws[d] = ds[d];
            if (act) {
                if (ww > 0)      ld_col_add(&A[(t-1) * CSTR], ws);
                if (ww < BOX-1)  ld_col_add(&A[(t+1) * CSTR], ws);
                st_col(&Bb[t * CSTR], ws);
            }
            __syncthreads();
            // h-pass: add h+-1 neighbor columns from B, multiply prob
            #pragma unroll
            for (int d = 0; d < BOX; ++d) c[d] = ws[d];
            if (act) {
                if (hh > 0)      ld_col_add(&Bb[(t-BOX) * CSTR], c);
                if (hh < BOX-1)  ld_col_add(&Bb[(t+BOX) * CSTR], c);
            }
            #pragma unroll
            for (int d = 0; d < BOX; ++d) {
                c[d] *= p[d];
                if (k == NIT-2) max9 = fmaxf(max9, c[d]);
                if (k == NIT-1) maxN = fmaxf(maxN, c[d]);
            }
        }

        // write final field (coalesced: fixed d -> consecutive lanes)
        if (act) {
            #pragma unroll
            for (int d = 0; d < BOX; ++d)
                u[(size_t)box * BOX3 + d * BOX2 + t] = c[d];
        }

        // reduce per-box maxes
        #pragma unroll
        for (int o = 32; o > 0; o >>= 1) {
            max9 = fmaxf(max9, __shfl_down(max9, o));
            maxN = fmaxf(maxN, __shfl_down(maxN, o));
        }
        if ((t & 63) == 0) { sred[t >> 6] = max9; sred2[t >> 6] = maxN; }
        __syncthreads();
        if (t == 0) {
            float m9 = sred[0], mN = sred2[0];
            #pragma unroll
            for (int i = 1; i < 7; ++i) { m9 = fmaxf(m9, sred[i]); mN = fmaxf(mN, sred2[i]); }
            g9part[box] = m9;
            gNpart[box] = mN;
        }
    }
    __syncthreads();

    // ---- arrival: last block runs the tail ---------------------------------
    if (t == 0) {
        __threadfence();
        unsigned int old = atomicAdd(counter, 1u);
        stail = (old == NBOX - 1) ? 1 : 0;
    }
    __syncthreads();
    if (!stail) return;
    __threadfence();   // acquire: other blocks' u/g writes now visible

    // ---- tail: overlap-corrected g_N, recurrence, gather -------------------
    __shared__ int sE[NBOX][3], sdup[NBOX], sovl[NBOX];
    __shared__ float sg9[NBOX], sgN[NBOX];
    __shared__ float bgN[BZ], bg9[BZ];
    if (t < NBOX) {
        sE[t][0] = ea[t*3]; sE[t][1] = ea[t*3+1]; sE[t][2] = ea[t*3+2];
        sdup[t] = dupflag[t];
        sg9[t] = g9part[t];
        sgN[t] = gNpart[t];
    }
    __syncthreads();
    if (t < NBOX) {
        int ov = 0;
        if (!sdup[t]) {
            int bb = t >> 5;
            for (int q = bb*NP; q < (bb+1)*NP; ++q) {
                if (q == t || sdup[q]) continue;
                if (abs(sE[q][0]-sE[t][0]) <= 2*RAD &&
                    abs(sE[q][1]-sE[t][1]) <= 2*RAD &&
                    abs(sE[q][2]-sE[t][2]) <= 2*RAD) { ov = 1; break; }
            }
        }
        sovl[t] = ov;
    }
    __syncthreads();
    // recompute summed-field max for overlapped boxes (expected: rare)
    for (int q = 0; q < NBOX; ++q) {
        if (!sovl[q]) continue;                    // shared -> block-uniform
        int bb = q >> 5;
        float m = 0.f;
        for (int i = t; i < BOX3; i += NT) {
            int d = i / BOX2, r = i % BOX2;
            int h = r / BOX, w = r % BOX;
            float v = u[(size_t)q * BOX3 + i];
            int gd = sE[q][0] - RAD + d, gh = sE[q][1] - RAD + h, gw = sE[q][2] - RAD + w;
            for (int j = bb*NP; j < (bb+1)*NP; ++j) {
                if (j == q || sdup[j]) continue;
                int ld = gd - sE[j][0] + RAD;
                int lh = gh - sE[j][1] + RAD;
                int lw = gw - sE[j][2] + RAD;
                if (ld >= 0 && ld < BOX && lh >= 0 && lh < BOX && lw >= 0 && lw < BOX)
                    v += u[(size_t)j * BOX3 + (ld*BOX + lh)*BOX + lw];
            }
            m = fmaxf(m, v);
        }
        #pragma unroll
        for (int o = 32; o > 0; o >>= 1) m = fmaxf(m, __shfl_down(m, o));
        if ((t & 63) == 0) sred[t >> 6] = m;
        __syncthreads();
        if (t == 0) {
            float mm = sred[0];
            #pragma unroll
            for (int i = 1; i < 7; ++i) mm = fmaxf(mm, sred[i]);
            sgN[q] = mm;
        }
        __syncthreads();
    }
    // per-batch gN, g9
    if (t < BZ) {
        float gN = 0.f, g9 = 0.f;
        for (int q = t*NP; q < (t+1)*NP; ++q) {
            gN = fmaxf(gN, sgN[q]);
            g9 = fmaxf(g9, sg9[q]);
        }
        bgN[t] = gN; bg9[t] = g9;
    }
    __syncthreads();
    // eb gather + reduce (threads 0..63 = wave 0)
    if (t < 64) {
        int bb = t >> 5;
        // t_N = g_N + eps*g_9 (higher eps powers < 1e-10 relative)
        float tden = bgN[bb] + SMOOTH * bg9[bb];
        int d = eb[t*3], h = eb[t*3+1], w = eb[t*3+2];
        float v = 0.f;
        for (int q = bb*NP; q < (bb+1)*NP; ++q) {
            if (sdup[q]) continue;
            int ld = d - sE[q][0] + RAD;
            int lh = h - sE[q][1] + RAD;
            int lw = w - sE[q][2] + RAD;
            if (ld >= 0 && ld < BOX && lh >= 0 && lh < BOX && lw >= 0 && lw < BOX)
                v += u[(size_t)q * BOX3 + (ld*BOX + lh)*BOX + lw];
        }
        float score = (tden > 0.f) ? v / tden : 0.f;
        #pragma unroll
        for (int o = 32; o > 0; o >>= 1) score += __shfl_down(score, o);
        if (t == 0) out[0] = 1.f - score / (float)NBOX;
    }
}

// ===========================================================================
extern "C" void kernel_launch(void* const* d_in, const int* in_sizes, int n_in,
                              void* d_out, int out_size, void* d_ws, size_t ws_size,
                              hipStream_t stream) {
    const float* logits = (const float*)d_in[0];
    // d_in[1] = labels (host-side only)
    const int* ea = (const int*)d_in[2];
    const int* eb = (const int*)d_in[3];
    float* out = (float*)d_out;

    float* u       = (float*)d_ws;                   // 64*9261 floats (~2.3 MB)
    float* g9part  = u + (size_t)NBOX * BOX3;        // 64
    float* gNpart  = g9part + NBOX;                  // 64
    int*   dflag   = (int*)(gNpart + NBOX);          // 64
    unsigned int* counter = (unsigned int*)(dflag + NBOX);

    hipMemsetAsync(counter, 0, sizeof(unsigned int), stream);
    cape_kernel<<<NBOX, NT, 0, stream>>>(logits, ea, eb, out,
                                         u, g9part, gNpart, dflag, counter);
}